// Round 7
// baseline (306.896 us; speedup 1.0000x reference)
//
#include <hip/hip_runtime.h>

// PaDiM training-branch accumulation + finalize.
// embeddings: [B=32, C=192, P=3136] f32; means: [P,C] f32; covariances: [P,C,C] f32; n: int
// out: learned_means [P,C] ++ learned_covs [P,C,C]
//
// R7: MFMA SYRK. K1 transposes emb -> Et bf16 [p][c][b] (row = 32 bf16 = 64B).
// K2: per (p, c-slab 96): A-frag[m=d][k=b] and B-frag[k=b][n=c] for
// mfma_f32_16x16x32_bf16 are each ONE contiguous 16B read per lane from Et
// (L1-resident 12KB/patch). No LDS staging at all in K2 -> LDS pipe (~70us/CU
// in R6) and VALU FMA (~47us) collapse to ~4us of MFMA; K2 becomes a pure
// nt cov RMW stream. SYRK symmetry makes C/D row/col and k-order ambiguities
// self-correcting. bf16 error ~1e-3 << 1.3e-2 threshold.

#define BB 32
#define CC 192
#define PP 3136
#define II (BB * CC)   // 6144
#define EPSV 0.01f

typedef float f32x4 __attribute__((ext_vector_type(4)));
typedef short bf16x8 __attribute__((ext_vector_type(8)));

__device__ __forceinline__ unsigned short f2bf(float f) {
    unsigned int u = __float_as_uint(f);
    u += 0x7fffu + ((u >> 16) & 1u);        // round-to-nearest-even
    return (unsigned short)(u >> 16);
}
__device__ __forceinline__ float bflo(unsigned int u) { return __uint_as_float(u << 16); }
__device__ __forceinline__ float bfhi(unsigned int u) { return __uint_as_float(u & 0xffff0000u); }

// ---------- Kernel 1: emb [B,C,P] f32 -> Et [P][C][B] bf16 ----------
// Block: 16 c x all 32 b x 32 p. Reads coalesced 128B row-segments; writes
// 8x128B contiguous segments per wave. LDS tile keyed r = cl*32 + b, pad 34.
__global__ __launch_bounds__(256) void transpose_bf16(
    const float* __restrict__ emb, unsigned short* __restrict__ Et)
{
    __shared__ unsigned short tile[512 * 34];   // 34816 B
    const int c0 = blockIdx.x * 16;             // 12 blocks over C
    const int p0 = blockIdx.y * 32;             // 98 blocks over P
    const int t = threadIdx.x;
    const int tc = t & 31;                      // p lane
    const int rg = t >> 5;                      // 0..7

    #pragma unroll 8
    for (int k = 0; k < 64; ++k) {
        const int r = k * 8 + rg;               // r = cl*32 + b
        const int b = r & 31;
        const int cl = r >> 5;
        const float v = __builtin_nontemporal_load(
            &emb[(size_t)(b * CC + c0 + cl) * PP + (p0 + tc)]);
        tile[r * 34 + tc] = f2bf(v);
    }
    __syncthreads();

    const int pl = t >> 3;                      // 0..31
    unsigned short* dst = Et + (size_t)(p0 + pl) * II + c0 * 32;
    #pragma unroll
    for (int w = 0; w < 8; ++w) {
        const int q = w * 8 + (t & 7);          // 16B chunk index (contig per wave)
        const int rbase = (q >> 2) * 32 + (q & 3) * 8;
        unsigned int dw[4];
        #pragma unroll
        for (int j = 0; j < 4; ++j) {
            const unsigned int lo = tile[(rbase + 2 * j) * 34 + pl];
            const unsigned int hi = tile[(rbase + 2 * j + 1) * 34 + pl];
            dw[j] = lo | (hi << 16);
        }
        uint4 val; val.x = dw[0]; val.y = dw[1]; val.z = dw[2]; val.w = dw[3];
        *reinterpret_cast<uint4*>(dst + q * 8) = val;
    }
}

// ---------- Kernel 2: MFMA SYRK + finalize, no LDS staging ----------
__global__ __launch_bounds__(256, 3) void padim_mfma(
    const unsigned short* __restrict__ Et,  // [P][C][B] bf16
    const float* __restrict__ means,        // [P,C]
    const float* __restrict__ covs,         // [P,C,C]
    const int*   __restrict__ n_ptr,
    float* __restrict__ out_means,          // [P,C]
    float* __restrict__ out_covs)           // [P,C,C]
{
    __shared__ float m_lds[CC];

    // XCD-bijective swizzle over 6272 blocks; slab pairs of one patch adjacent
    // within an XCD chunk so Et[p] (12KB) is L2/L1-shared.
    const int bid = blockIdx.x;
    const int u = (bid & 7) * (PP * 2 / 8) + (bid >> 3);
    const int slab = u & 1;                 // c-slab: cols slab*96..+95
    const int p = u >> 1;

    const int t = threadIdx.x;
    const int lane = t & 63;
    const int w = t >> 6;                   // wave 0..3: d-tiles 3w..3w+2
    const int l15 = lane & 15;
    const int l4  = lane >> 4;

    const float n_new = (float)(n_ptr[0] + BB);       // 128
    const float inv_nnew = 1.0f / n_new;
    const float inv_nm1 = 1.0f / (n_new - 1.0f);      // 1/127

    const unsigned short* __restrict__ Erow = Et + (size_t)p * II;

    // ---- Fragment loads (issued first; L1/L2-resident 12KB row) ----
    // mfma_f32_16x16x32_bf16: m/n = lane&15 (16 vals), k = (lane>>4)*8+j (32 vals).
    // A[m=d][k=b] and B[k=b][n=c] are both "row d-or-c, bytes (lane>>4)*16.."
    // of Et's 64B rows -> one 16B load each.
    bf16x8 Af[3], Bf[6];
    #pragma unroll
    for (int dt = 0; dt < 3; ++dt) {
        const int rA = (3 * w + dt) * 16 + l15;
        Af[dt] = *reinterpret_cast<const bf16x8*>(Erow + rA * 32 + l4 * 8);
    }
    #pragma unroll
    for (int ct = 0; ct < 6; ++ct) {
        const int rB = (slab * 6 + ct) * 16 + l15;
        Bf[ct] = *reinterpret_cast<const bf16x8*>(Erow + rB * 32 + l4 * 8);
    }

    // ---- Means: thread t sums row t of Et (32 bf16 = 4 x uint4) ----
    if (t < CC) {
        const uint4* rp = reinterpret_cast<const uint4*>(Erow + t * 32);
        float s = 0.f;
        #pragma unroll
        for (int q = 0; q < 4; ++q) {
            const uint4 v = rp[q];
            s += bflo(v.x) + bfhi(v.x) + bflo(v.y) + bfhi(v.y)
               + bflo(v.z) + bfhi(v.z) + bflo(v.w) + bfhi(v.w);
        }
        const float mm = (means[(size_t)p * CC + t] + s) * inv_nnew;
        m_lds[t] = mm;
        if (slab == 0) out_means[(size_t)p * CC + t] = mm;
    }
    __syncthreads();

    // ---- 18 MFMAs: acc[dt][ct] = full K=32 SYRK tile ----
    f32x4 acc[3][6];
    #pragma unroll
    for (int dt = 0; dt < 3; ++dt)
        #pragma unroll
        for (int ct = 0; ct < 6; ++ct)
            acc[dt][ct] = (f32x4){0.f, 0.f, 0.f, 0.f};

    #pragma unroll
    for (int ct = 0; ct < 6; ++ct)
        #pragma unroll
        for (int dt = 0; dt < 3; ++dt)
            acc[dt][ct] = __builtin_amdgcn_mfma_f32_16x16x32_bf16(
                Af[dt], Bf[ct], acc[dt][ct], 0, 0, 0);

    // ---- Finalize + nt cov RMW stream ----
    // C/D layout (m89): col = lane&15 -> c; row = (lane>>4)*4 + reg -> d.
    // Thread's 4 regs = cov[c][d0..d0+3] = one float4 of a cov row.
    const float* __restrict__ cov_p = covs + (size_t)p * CC * CC;
    float* __restrict__ out_p = out_covs + (size_t)p * CC * CC;

    #pragma unroll
    for (int dt = 0; dt < 3; ++dt) {
        const int d0 = (3 * w + dt) * 16 + l4 * 4;
        const f32x4 md = *reinterpret_cast<const f32x4*>(&m_lds[d0]);
        #pragma unroll
        for (int ct = 0; ct < 6; ++ct) {
            const int c = (slab * 6 + ct) * 16 + l15;
            const float nmc = n_new * m_lds[c];
            const size_t off = (size_t)c * CC + d0;
            const f32x4 cin = __builtin_nontemporal_load(
                reinterpret_cast<const f32x4*>(cov_p + off));
            f32x4 o = (cin + acc[dt][ct] - nmc * md) * inv_nm1;
            const int dd = c - d0;   // diagonal when 0 <= dd < 4
            o.x += (dd == 0) ? EPSV : 0.f;
            o.y += (dd == 1) ? EPSV : 0.f;
            o.z += (dd == 2) ? EPSV : 0.f;
            o.w += (dd == 3) ? EPSV : 0.f;
            __builtin_nontemporal_store(o, reinterpret_cast<f32x4*>(out_p + off));
        }
    }
}

// ---------- Fallback (ws too small): R6 single-kernel with direct gather ----
__global__ __launch_bounds__(256, 3) void padim_fallback(
    const float* __restrict__ emb, const float* __restrict__ means,
    const float* __restrict__ covs, const int* __restrict__ n_ptr,
    float* __restrict__ out_means, float* __restrict__ out_covs)
{
    __shared__ __align__(16) float E[II];
    __shared__ __align__(16) float m[CC];
    const int bid = blockIdx.x;
    const int p = (bid & 7) * (PP / 8) + (bid >> 3);
    const int t = threadIdx.x;
    const float n_new = (float)(n_ptr[0] + BB);
    const float inv_nnew = 1.0f / n_new;
    const float inv_nm1 = 1.0f / (n_new - 1.0f);
    #pragma unroll
    for (int k = 0; k < II / 256; ++k) {
        const int i = t + k * 256;
        E[i] = emb[(size_t)i * PP + p];
    }
    __syncthreads();
    if (t < CC) {
        float s = 0.0f;
        #pragma unroll
        for (int b = 0; b < BB; ++b) s += E[b * CC + t];
        const float mm = (means[(size_t)p * CC + t] + s) * inv_nnew;
        m[t] = mm;
        out_means[(size_t)p * CC + t] = mm;
    }
    __syncthreads();
    const int tx = t & 15, ty = t >> 4;
    const int dbase0 = tx * 4;
    const float* __restrict__ cov_p = covs + (size_t)p * CC * CC;
    float* __restrict__ out_p = out_covs + (size_t)p * CC * CC;
    float md[12];
    *reinterpret_cast<float4*>(&md[0]) = *reinterpret_cast<const float4*>(&m[dbase0]);
    *reinterpret_cast<float4*>(&md[4]) = *reinterpret_cast<const float4*>(&m[64 + dbase0]);
    *reinterpret_cast<float4*>(&md[8]) = *reinterpret_cast<const float4*>(&m[128 + dbase0]);
    #pragma unroll
    for (int pass = 0; pass < 2; ++pass) {
        const int c0 = pass * 96 + ty * 6;
        float acc[6][12];
        #pragma unroll
        for (int i = 0; i < 6; ++i)
            #pragma unroll
            for (int j = 0; j < 12; ++j) acc[i][j] = 0.f;
        #pragma unroll 4
        for (int b = 0; b < BB; ++b) {
            const float* __restrict__ Eb = E + b * CC;
            float cs[6], ds[12];
            *reinterpret_cast<float4*>(&ds[0]) = *reinterpret_cast<const float4*>(&Eb[dbase0]);
            *reinterpret_cast<float4*>(&ds[4]) = *reinterpret_cast<const float4*>(&Eb[64 + dbase0]);
            *reinterpret_cast<float4*>(&ds[8]) = *reinterpret_cast<const float4*>(&Eb[128 + dbase0]);
            *reinterpret_cast<float2*>(&cs[0]) = *reinterpret_cast<const float2*>(&Eb[c0]);
            *reinterpret_cast<float2*>(&cs[2]) = *reinterpret_cast<const float2*>(&Eb[c0 + 2]);
            *reinterpret_cast<float2*>(&cs[4]) = *reinterpret_cast<const float2*>(&Eb[c0 + 4]);
            #pragma unroll
            for (int i = 0; i < 6; ++i)
                #pragma unroll
                for (int j = 0; j < 12; ++j)
                    acc[i][j] = fmaf(cs[i], ds[j], acc[i][j]);
        }
        float mc[6];
        *reinterpret_cast<float2*>(&mc[0]) = *reinterpret_cast<const float2*>(&m[c0]);
        *reinterpret_cast<float2*>(&mc[2]) = *reinterpret_cast<const float2*>(&m[c0 + 2]);
        *reinterpret_cast<float2*>(&mc[4]) = *reinterpret_cast<const float2*>(&m[c0 + 4]);
        #pragma unroll
        for (int i = 0; i < 6; ++i) {
            const int c = c0 + i;
            const size_t row = (size_t)c * CC;
            const float nmc = n_new * mc[i];
            #pragma unroll
            for (int g = 0; g < 3; ++g) {
                const int db = g * 64 + dbase0;
                const float4 cin = *reinterpret_cast<const float4*>(&cov_p[row + db]);
                float4 o;
                o.x = (cin.x + acc[i][g*4+0] - nmc * md[g*4+0]) * inv_nm1;
                o.y = (cin.y + acc[i][g*4+1] - nmc * md[g*4+1]) * inv_nm1;
                o.z = (cin.z + acc[i][g*4+2] - nmc * md[g*4+2]) * inv_nm1;
                o.w = (cin.w + acc[i][g*4+3] - nmc * md[g*4+3]) * inv_nm1;
                const int dd = c - db;
                if (dd == 0) o.x += EPSV;
                if (dd == 1) o.y += EPSV;
                if (dd == 2) o.z += EPSV;
                if (dd == 3) o.w += EPSV;
                *reinterpret_cast<float4*>(&out_p[row + db]) = o;
            }
        }
    }
}

extern "C" void kernel_launch(void* const* d_in, const int* in_sizes, int n_in,
                              void* d_out, int out_size, void* d_ws, size_t ws_size,
                              hipStream_t stream) {
    const float* emb   = (const float*)d_in[0];
    const float* means = (const float*)d_in[1];
    const float* covs  = (const float*)d_in[2];
    const int*   n_ptr = (const int*)d_in[3];

    float* out_means = (float*)d_out;                      // [P,C]
    float* out_covs  = (float*)d_out + (size_t)PP * CC;    // [P,C,C]

    const size_t et_bytes = (size_t)PP * II * sizeof(unsigned short);   // 38.5 MB
    if (ws_size >= et_bytes) {
        unsigned short* Et = (unsigned short*)d_ws;
        hipLaunchKernelGGL(transpose_bf16, dim3(CC / 16, PP / 32), dim3(256),
                           0, stream, emb, Et);
        hipLaunchKernelGGL(padim_mfma, dim3(PP * 2), dim3(256), 0, stream,
                           Et, means, covs, n_ptr, out_means, out_covs);
    } else {
        hipLaunchKernelGGL(padim_fallback, dim3(PP), dim3(256), 0, stream,
                           emb, means, covs, n_ptr, out_means, out_covs);
    }
}

// Round 8
// 297.069 us; speedup vs baseline: 1.0331x; 1.0331x over previous
//
#include <hip/hip_runtime.h>

// PaDiM training-branch accumulation + finalize.
// embeddings: [B=32, C=192, P=3136] f32; means: [P,C] f32; covariances: [P,C,C] f32; n: int
// out: learned_means [P,C] ++ learned_covs [P,C,C]
//
// R8: MFMA SYRK + LDS-transpose epilogue. R7's regression was the C/D lane
// layout scattering the cov RMW (16 rows x 16B per wave instr). Now each
// wave stages its acc tiles into LDS [16][196] (2-way bank alias = free),
// and the readback RMW is fully coalesced (768B contiguous per row, float4
// nt load + nt store). K1 (bf16 Et [p][c][b] transpose) unchanged from R7.

#define BB 32
#define CC 192
#define PP 3136
#define II (BB * CC)   // 6144
#define EPSV 0.01f
#define LDSW 196       // padded row stride (floats) for epilogue buffer

typedef float f32x4 __attribute__((ext_vector_type(4)));
typedef short bf16x8 __attribute__((ext_vector_type(8)));

__device__ __forceinline__ unsigned short f2bf(float f) {
    unsigned int u = __float_as_uint(f);
    u += 0x7fffu + ((u >> 16) & 1u);        // round-to-nearest-even
    return (unsigned short)(u >> 16);
}
__device__ __forceinline__ float bflo(unsigned int u) { return __uint_as_float(u << 16); }
__device__ __forceinline__ float bfhi(unsigned int u) { return __uint_as_float(u & 0xffff0000u); }

// ---------- Kernel 1: emb [B,C,P] f32 -> Et [P][C][B] bf16 ----------
__global__ __launch_bounds__(256) void transpose_bf16(
    const float* __restrict__ emb, unsigned short* __restrict__ Et)
{
    __shared__ unsigned short tile[512 * 34];   // 34816 B
    const int c0 = blockIdx.x * 16;             // 12 blocks over C
    const int p0 = blockIdx.y * 32;             // 98 blocks over P
    const int t = threadIdx.x;
    const int tc = t & 31;                      // p lane
    const int rg = t >> 5;                      // 0..7

    #pragma unroll 8
    for (int k = 0; k < 64; ++k) {
        const int r = k * 8 + rg;               // r = cl*32 + b
        const int b = r & 31;
        const int cl = r >> 5;
        const float v = __builtin_nontemporal_load(
            &emb[(size_t)(b * CC + c0 + cl) * PP + (p0 + tc)]);
        tile[r * 34 + tc] = f2bf(v);
    }
    __syncthreads();

    const int pl = t >> 3;                      // 0..31
    unsigned short* dst = Et + (size_t)(p0 + pl) * II + c0 * 32;
    #pragma unroll
    for (int w = 0; w < 8; ++w) {
        const int q = w * 8 + (t & 7);          // 16B chunk index (contig per wave)
        const int rbase = (q >> 2) * 32 + (q & 3) * 8;
        unsigned int dw[4];
        #pragma unroll
        for (int j = 0; j < 4; ++j) {
            const unsigned int lo = tile[(rbase + 2 * j) * 34 + pl];
            const unsigned int hi = tile[(rbase + 2 * j + 1) * 34 + pl];
            dw[j] = lo | (hi << 16);
        }
        uint4 val; val.x = dw[0]; val.y = dw[1]; val.z = dw[2]; val.w = dw[3];
        *reinterpret_cast<uint4*>(dst + q * 8) = val;
    }
}

// ---------- Kernel 2: MFMA SYRK + LDS-transpose epilogue ----------
__global__ __launch_bounds__(256, 3) void padim_mfma(
    const unsigned short* __restrict__ Et,  // [P][C][B] bf16
    const float* __restrict__ means,        // [P,C]
    const float* __restrict__ covs,         // [P,C,C]
    const int*   __restrict__ n_ptr,
    float* __restrict__ out_means,          // [P,C]
    float* __restrict__ out_covs)           // [P,C,C]
{
    __shared__ float m_lds[CC];
    __shared__ __align__(16) float ebuf[2][16 * LDSW];   // 2 x 12544 B

    // XCD-bijective swizzle; the two slabs of one patch stay adjacent (L2
    // shares the 12KB Et row).
    const int bid = blockIdx.x;
    const int u = (bid & 7) * (PP * 2 / 8) + (bid >> 3);
    const int slab = u & 1;                 // c-slab: rows slab*96..+95
    const int p = u >> 1;

    const int t = threadIdx.x;
    const int lane = t & 63;
    const int w = t >> 6;                   // wave 0..3: d-tiles 3w..3w+2
    const int l15 = lane & 15;
    const int l4  = lane >> 4;

    const float n_new = (float)(n_ptr[0] + BB);       // 128
    const float inv_nnew = 1.0f / n_new;
    const float inv_nm1 = 1.0f / (n_new - 1.0f);      // 1/127

    const unsigned short* __restrict__ Erow = Et + (size_t)p * II;

    // ---- Fragment loads: contiguous 1KB per wave instruction ----
    bf16x8 Af[3], Bf[6];
    #pragma unroll
    for (int dt = 0; dt < 3; ++dt) {
        const int rA = (3 * w + dt) * 16 + l15;
        Af[dt] = *reinterpret_cast<const bf16x8*>(Erow + rA * 32 + l4 * 8);
    }
    #pragma unroll
    for (int ct = 0; ct < 6; ++ct) {
        const int rB = (slab * 6 + ct) * 16 + l15;
        Bf[ct] = *reinterpret_cast<const bf16x8*>(Erow + rB * 32 + l4 * 8);
    }

    // ---- Means: thread t sums row t of Et ----
    if (t < CC) {
        const uint4* rp = reinterpret_cast<const uint4*>(Erow + t * 32);
        float s = 0.f;
        #pragma unroll
        for (int q = 0; q < 4; ++q) {
            const uint4 v = rp[q];
            s += bflo(v.x) + bfhi(v.x) + bflo(v.y) + bfhi(v.y)
               + bflo(v.z) + bfhi(v.z) + bflo(v.w) + bfhi(v.w);
        }
        const float mm = (means[(size_t)p * CC + t] + s) * inv_nnew;
        m_lds[t] = mm;
        if (slab == 0) out_means[(size_t)p * CC + t] = mm;
    }
    __syncthreads();

    // ---- 18 MFMAs (full K=32 per tile) ----
    f32x4 acc[3][6];
    #pragma unroll
    for (int dt = 0; dt < 3; ++dt)
        #pragma unroll
        for (int ct = 0; ct < 6; ++ct)
            acc[dt][ct] = (f32x4){0.f, 0.f, 0.f, 0.f};

    #pragma unroll
    for (int ct = 0; ct < 6; ++ct)
        #pragma unroll
        for (int dt = 0; dt < 3; ++dt)
            acc[dt][ct] = __builtin_amdgcn_mfma_f32_16x16x32_bf16(
                Af[dt], Bf[ct], acc[dt][ct], 0, 0, 0);

    // ---- Epilogue: per c-tile, LDS transpose then coalesced cov RMW ----
    // acc layout (m89): value at cov row c = ct*16 + (lane&15),
    // cols d = (3w+dt)*16 + l4*4 + reg. Stage into ebuf[c_local][d],
    // read back row-major (48 lanes = 768B contiguous per row).
    const float* __restrict__ cov_p = covs + (size_t)p * CC * CC;
    float* __restrict__ out_p = out_covs + (size_t)p * CC * CC;

    #pragma unroll 1
    for (int ct = 0; ct < 6; ++ct) {
        float* buf = ebuf[ct & 1];
        #pragma unroll
        for (int dt = 0; dt < 3; ++dt) {
            const int q = (3 * w + dt) * 4 + l4;       // 16B chunk 0..47
            *reinterpret_cast<f32x4*>(&buf[l15 * LDSW + q * 4]) = acc[dt][ct];
        }
        __syncthreads();
        #pragma unroll
        for (int k = 0; k < 3; ++k) {
            const int f = t + 256 * k;                 // 0..767
            const int r = f / 48;                      // row 0..15
            const int q = f - r * 48;                  // chunk 0..47
            const int c = (slab * 6 + ct) * 16 + r;
            const int d = q * 4;
            const f32x4 a = *reinterpret_cast<const f32x4*>(&buf[r * LDSW + d]);
            const size_t off = (size_t)c * CC + d;
            const f32x4 cin = __builtin_nontemporal_load(
                reinterpret_cast<const f32x4*>(cov_p + off));
            const f32x4 md = *reinterpret_cast<const f32x4*>(&m_lds[d]);
            const float nmc = n_new * m_lds[c];
            f32x4 o = (cin + a - nmc * md) * inv_nm1;
            const int dd = c - d;                      // diagonal when 0<=dd<4
            o.x += (dd == 0) ? EPSV : 0.f;
            o.y += (dd == 1) ? EPSV : 0.f;
            o.z += (dd == 2) ? EPSV : 0.f;
            o.w += (dd == 3) ? EPSV : 0.f;
            __builtin_nontemporal_store(o, reinterpret_cast<f32x4*>(out_p + off));
        }
        // next iter writes the other buffer; barrier above orders reuse
    }
}

// ---------- Fallback (ws too small): single-kernel with direct gather ----
__global__ __launch_bounds__(256, 3) void padim_fallback(
    const float* __restrict__ emb, const float* __restrict__ means,
    const float* __restrict__ covs, const int* __restrict__ n_ptr,
    float* __restrict__ out_means, float* __restrict__ out_covs)
{
    __shared__ __align__(16) float E[II];
    __shared__ __align__(16) float m[CC];
    const int bid = blockIdx.x;
    const int p = (bid & 7) * (PP / 8) + (bid >> 3);
    const int t = threadIdx.x;
    const float n_new = (float)(n_ptr[0] + BB);
    const float inv_nnew = 1.0f / n_new;
    const float inv_nm1 = 1.0f / (n_new - 1.0f);
    #pragma unroll
    for (int k = 0; k < II / 256; ++k) {
        const int i = t + k * 256;
        E[i] = emb[(size_t)i * PP + p];
    }
    __syncthreads();
    if (t < CC) {
        float s = 0.0f;
        #pragma unroll
        for (int b = 0; b < BB; ++b) s += E[b * CC + t];
        const float mm = (means[(size_t)p * CC + t] + s) * inv_nnew;
        m[t] = mm;
        out_means[(size_t)p * CC + t] = mm;
    }
    __syncthreads();
    const int tx = t & 15, ty = t >> 4;
    const int dbase0 = tx * 4;
    const float* __restrict__ cov_p = covs + (size_t)p * CC * CC;
    float* __restrict__ out_p = out_covs + (size_t)p * CC * CC;
    float md[12];
    *reinterpret_cast<float4*>(&md[0]) = *reinterpret_cast<const float4*>(&m[dbase0]);
    *reinterpret_cast<float4*>(&md[4]) = *reinterpret_cast<const float4*>(&m[64 + dbase0]);
    *reinterpret_cast<float4*>(&md[8]) = *reinterpret_cast<const float4*>(&m[128 + dbase0]);
    #pragma unroll
    for (int pass = 0; pass < 2; ++pass) {
        const int c0 = pass * 96 + ty * 6;
        float acc[6][12];
        #pragma unroll
        for (int i = 0; i < 6; ++i)
            #pragma unroll
            for (int j = 0; j < 12; ++j) acc[i][j] = 0.f;
        #pragma unroll 4
        for (int b = 0; b < BB; ++b) {
            const float* __restrict__ Eb = E + b * CC;
            float cs[6], ds[12];
            *reinterpret_cast<float4*>(&ds[0]) = *reinterpret_cast<const float4*>(&Eb[dbase0]);
            *reinterpret_cast<float4*>(&ds[4]) = *reinterpret_cast<const float4*>(&Eb[64 + dbase0]);
            *reinterpret_cast<float4*>(&ds[8]) = *reinterpret_cast<const float4*>(&Eb[128 + dbase0]);
            *reinterpret_cast<float2*>(&cs[0]) = *reinterpret_cast<const float2*>(&Eb[c0]);
            *reinterpret_cast<float2*>(&cs[2]) = *reinterpret_cast<const float2*>(&Eb[c0 + 2]);
            *reinterpret_cast<float2*>(&cs[4]) = *reinterpret_cast<const float2*>(&Eb[c0 + 4]);
            #pragma unroll
            for (int i = 0; i < 6; ++i)
                #pragma unroll
                for (int j = 0; j < 12; ++j)
                    acc[i][j] = fmaf(cs[i], ds[j], acc[i][j]);
        }
        float mc[6];
        *reinterpret_cast<float2*>(&mc[0]) = *reinterpret_cast<const float2*>(&m[c0]);
        *reinterpret_cast<float2*>(&mc[2]) = *reinterpret_cast<const float2*>(&m[c0 + 2]);
        *reinterpret_cast<float2*>(&mc[4]) = *reinterpret_cast<const float2*>(&m[c0 + 4]);
        #pragma unroll
        for (int i = 0; i < 6; ++i) {
            const int c = c0 + i;
            const size_t row = (size_t)c * CC;
            const float nmc = n_new * mc[i];
            #pragma unroll
            for (int g = 0; g < 3; ++g) {
                const int db = g * 64 + dbase0;
                const float4 cin = *reinterpret_cast<const float4*>(&cov_p[row + db]);
                float4 o;
                o.x = (cin.x + acc[i][g*4+0] - nmc * md[g*4+0]) * inv_nm1;
                o.y = (cin.y + acc[i][g*4+1] - nmc * md[g*4+1]) * inv_nm1;
                o.z = (cin.z + acc[i][g*4+2] - nmc * md[g*4+2]) * inv_nm1;
                o.w = (cin.w + acc[i][g*4+3] - nmc * md[g*4+3]) * inv_nm1;
                const int dd = c - db;
                if (dd == 0) o.x += EPSV;
                if (dd == 1) o.y += EPSV;
                if (dd == 2) o.z += EPSV;
                if (dd == 3) o.w += EPSV;
                *reinterpret_cast<float4*>(&out_p[row + db]) = o;
            }
        }
    }
}

extern "C" void kernel_launch(void* const* d_in, const int* in_sizes, int n_in,
                              void* d_out, int out_size, void* d_ws, size_t ws_size,
                              hipStream_t stream) {
    const float* emb   = (const float*)d_in[0];
    const float* means = (const float*)d_in[1];
    const float* covs  = (const float*)d_in[2];
    const int*   n_ptr = (const int*)d_in[3];

    float* out_means = (float*)d_out;                      // [P,C]
    float* out_covs  = (float*)d_out + (size_t)PP * CC;    // [P,C,C]

    const size_t et_bytes = (size_t)PP * II * sizeof(unsigned short);   // 38.5 MB
    if (ws_size >= et_bytes) {
        unsigned short* Et = (unsigned short*)d_ws;
        hipLaunchKernelGGL(transpose_bf16, dim3(CC / 16, PP / 32), dim3(256),
                           0, stream, emb, Et);
        hipLaunchKernelGGL(padim_mfma, dim3(PP * 2), dim3(256), 0, stream,
                           Et, means, covs, n_ptr, out_means, out_covs);
    } else {
        hipLaunchKernelGGL(padim_fallback, dim3(PP), dim3(256), 0, stream,
                           emb, means, covs, n_ptr, out_means, out_covs);
    }
}

// Round 9
// 219.058 us; speedup vs baseline: 1.4010x; 1.3561x over previous
//
#include <hip/hip_runtime.h>

// PaDiM training-branch accumulation + finalize.
// embeddings: [B=32, C=192, P=3136] f32; means: [P,C] f32; covariances: [P,C,C] f32; n: int
// out: learned_means [P,C] ++ learned_covs [P,C,C]
//
// R9: MFMA SYRK + wave-private LDS-transpose epilogue, PLAIN stores.
// R8 anomaly: WRITE_SIZE = 2x ideal (905MB) with 1KB-contiguous nt stores;
// R5/R6 nt stores (256B segments) were exact. Fix: plain stores via L2
// (full-line dirtying guaranteed: all tile boundaries %64==0 -> 1 writeback
// per line), and drop nt loads on cov too (empirical safety). Epilogue is
// now wave-private: wave w owns cov cols [48w,48w+48); transpose via own
// LDS buffer (parity dbuf) -> ZERO epilogue barriers, waves drift and
// overlap MFMA/LDS/RMW phases. Readback = 192B contiguous segments.

#define BB 32
#define CC 192
#define PP 3136
#define II (BB * CC)   // 6144
#define EPSV 0.01f
#define WROW 52        // padded row stride (floats) of wave buffer (48+4)

typedef float f32x4 __attribute__((ext_vector_type(4)));
typedef short bf16x8 __attribute__((ext_vector_type(8)));

__device__ __forceinline__ unsigned short f2bf(float f) {
    unsigned int u = __float_as_uint(f);
    u += 0x7fffu + ((u >> 16) & 1u);        // round-to-nearest-even
    return (unsigned short)(u >> 16);
}
__device__ __forceinline__ float bflo(unsigned int u) { return __uint_as_float(u << 16); }
__device__ __forceinline__ float bfhi(unsigned int u) { return __uint_as_float(u & 0xffff0000u); }

// ---------- Kernel 1: emb [B,C,P] f32 -> Et [P][C][B] bf16 ----------
__global__ __launch_bounds__(256) void transpose_bf16(
    const float* __restrict__ emb, unsigned short* __restrict__ Et)
{
    __shared__ unsigned short tile[512 * 34];   // 34816 B
    const int c0 = blockIdx.x * 16;             // 12 blocks over C
    const int p0 = blockIdx.y * 32;             // 98 blocks over P
    const int t = threadIdx.x;
    const int tc = t & 31;                      // p lane
    const int rg = t >> 5;                      // 0..7

    #pragma unroll 8
    for (int k = 0; k < 64; ++k) {
        const int r = k * 8 + rg;               // r = cl*32 + b
        const int b = r & 31;
        const int cl = r >> 5;
        const float v = __builtin_nontemporal_load(
            &emb[(size_t)(b * CC + c0 + cl) * PP + (p0 + tc)]);
        tile[r * 34 + tc] = f2bf(v);
    }
    __syncthreads();

    const int pl = t >> 3;                      // 0..31
    unsigned short* dst = Et + (size_t)(p0 + pl) * II + c0 * 32;
    #pragma unroll
    for (int w = 0; w < 8; ++w) {
        const int q = w * 8 + (t & 7);          // 16B chunk index (contig per wave)
        const int rbase = (q >> 2) * 32 + (q & 3) * 8;
        unsigned int dw[4];
        #pragma unroll
        for (int j = 0; j < 4; ++j) {
            const unsigned int lo = tile[(rbase + 2 * j) * 34 + pl];
            const unsigned int hi = tile[(rbase + 2 * j + 1) * 34 + pl];
            dw[j] = lo | (hi << 16);
        }
        uint4 val; val.x = dw[0]; val.y = dw[1]; val.z = dw[2]; val.w = dw[3];
        *reinterpret_cast<uint4*>(dst + q * 8) = val;
    }
}

// ---------- Kernel 2: MFMA SYRK + wave-private transpose epilogue ----------
__global__ __launch_bounds__(256, 3) void padim_mfma(
    const unsigned short* __restrict__ Et,  // [P][C][B] bf16
    const float* __restrict__ means,        // [P,C]
    const float* __restrict__ covs,         // [P,C,C]
    const int*   __restrict__ n_ptr,
    float* __restrict__ out_means,          // [P,C]
    float* __restrict__ out_covs)           // [P,C,C]
{
    __shared__ float m_lds[CC];
    __shared__ __align__(16) float wbuf[4][2][16 * WROW];   // 26624 B

    // XCD-bijective swizzle; the two slabs of one patch stay adjacent.
    const int bid = blockIdx.x;
    const int u = (bid & 7) * (PP * 2 / 8) + (bid >> 3);
    const int slab = u & 1;                 // c-slab: rows slab*96..+95
    const int p = u >> 1;

    const int t = threadIdx.x;
    const int lane = t & 63;
    const int w = t >> 6;                   // wave 0..3: owns cov cols [48w,48w+48)
    const int l15 = lane & 15;
    const int l4  = lane >> 4;

    const float n_new = (float)(n_ptr[0] + BB);       // 128
    const float inv_nnew = 1.0f / n_new;
    const float inv_nm1 = 1.0f / (n_new - 1.0f);      // 1/127

    const unsigned short* __restrict__ Erow = Et + (size_t)p * II;

    // ---- Fragment loads: contiguous 1KB per wave instruction ----
    bf16x8 Af[3], Bf[6];
    #pragma unroll
    for (int dt = 0; dt < 3; ++dt) {
        const int rA = (3 * w + dt) * 16 + l15;
        Af[dt] = *reinterpret_cast<const bf16x8*>(Erow + rA * 32 + l4 * 8);
    }
    #pragma unroll
    for (int ct = 0; ct < 6; ++ct) {
        const int rB = (slab * 6 + ct) * 16 + l15;
        Bf[ct] = *reinterpret_cast<const bf16x8*>(Erow + rB * 32 + l4 * 8);
    }

    // ---- Means: thread t sums row t of Et ----
    if (t < CC) {
        const uint4* rp = reinterpret_cast<const uint4*>(Erow + t * 32);
        float s = 0.f;
        #pragma unroll
        for (int q = 0; q < 4; ++q) {
            const uint4 v = rp[q];
            s += bflo(v.x) + bfhi(v.x) + bflo(v.y) + bfhi(v.y)
               + bflo(v.z) + bfhi(v.z) + bflo(v.w) + bfhi(v.w);
        }
        const float mm = (means[(size_t)p * CC + t] + s) * inv_nnew;
        m_lds[t] = mm;
        if (slab == 0) out_means[(size_t)p * CC + t] = mm;
    }
    __syncthreads();   // the only block barrier

    // ---- 18 MFMAs (full K=32 per tile) ----
    f32x4 acc[3][6];
    #pragma unroll
    for (int dt = 0; dt < 3; ++dt)
        #pragma unroll
        for (int ct = 0; ct < 6; ++ct)
            acc[dt][ct] = (f32x4){0.f, 0.f, 0.f, 0.f};

    #pragma unroll
    for (int ct = 0; ct < 6; ++ct)
        #pragma unroll
        for (int dt = 0; dt < 3; ++dt)
            acc[dt][ct] = __builtin_amdgcn_mfma_f32_16x16x32_bf16(
                Af[dt], Bf[ct], acc[dt][ct], 0, 0, 0);

    // ---- Wave-private epilogue: transpose 16x48 tile in own LDS buffer ----
    // acc layout (m89): value = cov(c = cbase + l15, d = 48w + dt*16 + l4*4 + reg).
    // ds_write [l15][dt*16+l4*4..+3]; readback chunk = k*64+lane over [16][12]
    // 16B chunks: r = chunk/12, q = chunk%12 -> 192B contiguous global segments.
    const float* __restrict__ cov_p = covs + (size_t)p * CC * CC;
    float* __restrict__ out_p = out_covs + (size_t)p * CC * CC;

    int rk[3], qk[3];
    f32x4 mdk[3];
    size_t offb[3];
    #pragma unroll
    for (int k = 0; k < 3; ++k) {
        const int chunk = k * 64 + lane;
        rk[k] = chunk / 12;
        qk[k] = chunk - rk[k] * 12;
        mdk[k] = *reinterpret_cast<const f32x4*>(&m_lds[48 * w + 4 * qk[k]]);
        offb[k] = (size_t)rk[k] * CC + 48 * w + 4 * qk[k];
    }

    #pragma unroll
    for (int ct = 0; ct < 6; ++ct) {
        const int cbase = (slab * 6 + ct) * 16;
        float* buf = &wbuf[w][ct & 1][0];

        // issue cov loads first (hide HBM latency under LDS transpose)
        f32x4 cin[3];
        #pragma unroll
        for (int k = 0; k < 3; ++k)
            cin[k] = *reinterpret_cast<const f32x4*>(cov_p + (size_t)cbase * CC + offb[k]);

        #pragma unroll
        for (int dt = 0; dt < 3; ++dt)
            *reinterpret_cast<f32x4*>(&buf[l15 * WROW + (dt * 4 + l4) * 4]) = acc[dt][ct];

        #pragma unroll
        for (int k = 0; k < 3; ++k) {
            const f32x4 a = *reinterpret_cast<const f32x4*>(&buf[rk[k] * WROW + 4 * qk[k]]);
            const int c = cbase + rk[k];
            const float nmc = n_new * m_lds[c];
            f32x4 o = (cin[k] + a - nmc * mdk[k]) * inv_nm1;
            const int dd = c - (48 * w + 4 * qk[k]);   // diagonal when 0<=dd<4
            o.x += (dd == 0) ? EPSV : 0.f;
            o.y += (dd == 1) ? EPSV : 0.f;
            o.z += (dd == 2) ? EPSV : 0.f;
            o.w += (dd == 3) ? EPSV : 0.f;
            *reinterpret_cast<f32x4*>(out_p + (size_t)cbase * CC + offb[k]) = o;
        }
    }
}

// ---------- Fallback (ws too small): single-kernel with direct gather ----
__global__ __launch_bounds__(256, 3) void padim_fallback(
    const float* __restrict__ emb, const float* __restrict__ means,
    const float* __restrict__ covs, const int* __restrict__ n_ptr,
    float* __restrict__ out_means, float* __restrict__ out_covs)
{
    __shared__ __align__(16) float E[II];
    __shared__ __align__(16) float m[CC];
    const int bid = blockIdx.x;
    const int p = (bid & 7) * (PP / 8) + (bid >> 3);
    const int t = threadIdx.x;
    const float n_new = (float)(n_ptr[0] + BB);
    const float inv_nnew = 1.0f / n_new;
    const float inv_nm1 = 1.0f / (n_new - 1.0f);
    #pragma unroll
    for (int k = 0; k < II / 256; ++k) {
        const int i = t + k * 256;
        E[i] = emb[(size_t)i * PP + p];
    }
    __syncthreads();
    if (t < CC) {
        float s = 0.0f;
        #pragma unroll
        for (int b = 0; b < BB; ++b) s += E[b * CC + t];
        const float mm = (means[(size_t)p * CC + t] + s) * inv_nnew;
        m[t] = mm;
        out_means[(size_t)p * CC + t] = mm;
    }
    __syncthreads();
    const int tx = t & 15, ty = t >> 4;
    const int dbase0 = tx * 4;
    const float* __restrict__ cov_p = covs + (size_t)p * CC * CC;
    float* __restrict__ out_p = out_covs + (size_t)p * CC * CC;
    float md[12];
    *reinterpret_cast<float4*>(&md[0]) = *reinterpret_cast<const float4*>(&m[dbase0]);
    *reinterpret_cast<float4*>(&md[4]) = *reinterpret_cast<const float4*>(&m[64 + dbase0]);
    *reinterpret_cast<float4*>(&md[8]) = *reinterpret_cast<const float4*>(&m[128 + dbase0]);
    #pragma unroll
    for (int pass = 0; pass < 2; ++pass) {
        const int c0 = pass * 96 + ty * 6;
        float acc[6][12];
        #pragma unroll
        for (int i = 0; i < 6; ++i)
            #pragma unroll
            for (int j = 0; j < 12; ++j) acc[i][j] = 0.f;
        #pragma unroll 4
        for (int b = 0; b < BB; ++b) {
            const float* __restrict__ Eb = E + b * CC;
            float cs[6], ds[12];
            *reinterpret_cast<float4*>(&ds[0]) = *reinterpret_cast<const float4*>(&Eb[dbase0]);
            *reinterpret_cast<float4*>(&ds[4]) = *reinterpret_cast<const float4*>(&Eb[64 + dbase0]);
            *reinterpret_cast<float4*>(&ds[8]) = *reinterpret_cast<const float4*>(&Eb[128 + dbase0]);
            *reinterpret_cast<float2*>(&cs[0]) = *reinterpret_cast<const float2*>(&Eb[c0]);
            *reinterpret_cast<float2*>(&cs[2]) = *reinterpret_cast<const float2*>(&Eb[c0 + 2]);
            *reinterpret_cast<float2*>(&cs[4]) = *reinterpret_cast<const float2*>(&Eb[c0 + 4]);
            #pragma unroll
            for (int i = 0; i < 6; ++i)
                #pragma unroll
                for (int j = 0; j < 12; ++j)
                    acc[i][j] = fmaf(cs[i], ds[j], acc[i][j]);
        }
        float mc[6];
        *reinterpret_cast<float2*>(&mc[0]) = *reinterpret_cast<const float2*>(&m[c0]);
        *reinterpret_cast<float2*>(&mc[2]) = *reinterpret_cast<const float2*>(&m[c0 + 2]);
        *reinterpret_cast<float2*>(&mc[4]) = *reinterpret_cast<const float2*>(&m[c0 + 4]);
        #pragma unroll
        for (int i = 0; i < 6; ++i) {
            const int c = c0 + i;
            const size_t row = (size_t)c * CC;
            const float nmc = n_new * mc[i];
            #pragma unroll
            for (int g = 0; g < 3; ++g) {
                const int db = g * 64 + dbase0;
                const float4 cin = *reinterpret_cast<const float4*>(&cov_p[row + db]);
                float4 o;
                o.x = (cin.x + acc[i][g*4+0] - nmc * md[g*4+0]) * inv_nm1;
                o.y = (cin.y + acc[i][g*4+1] - nmc * md[g*4+1]) * inv_nm1;
                o.z = (cin.z + acc[i][g*4+2] - nmc * md[g*4+2]) * inv_nm1;
                o.w = (cin.w + acc[i][g*4+3] - nmc * md[g*4+3]) * inv_nm1;
                const int dd = c - db;
                if (dd == 0) o.x += EPSV;
                if (dd == 1) o.y += EPSV;
                if (dd == 2) o.z += EPSV;
                if (dd == 3) o.w += EPSV;
                *reinterpret_cast<float4*>(&out_p[row + db]) = o;
            }
        }
    }
}

extern "C" void kernel_launch(void* const* d_in, const int* in_sizes, int n_in,
                              void* d_out, int out_size, void* d_ws, size_t ws_size,
                              hipStream_t stream) {
    const float* emb   = (const float*)d_in[0];
    const float* means = (const float*)d_in[1];
    const float* covs  = (const float*)d_in[2];
    const int*   n_ptr = (const int*)d_in[3];

    float* out_means = (float*)d_out;                      // [P,C]
    float* out_covs  = (float*)d_out + (size_t)PP * CC;    // [P,C,C]

    const size_t et_bytes = (size_t)PP * II * sizeof(unsigned short);   // 38.5 MB
    if (ws_size >= et_bytes) {
        unsigned short* Et = (unsigned short*)d_ws;
        hipLaunchKernelGGL(transpose_bf16, dim3(CC / 16, PP / 32), dim3(256),
                           0, stream, emb, Et);
        hipLaunchKernelGGL(padim_mfma, dim3(PP * 2), dim3(256), 0, stream,
                           Et, means, covs, n_ptr, out_means, out_covs);
    } else {
        hipLaunchKernelGGL(padim_fallback, dim3(PP), dim3(256), 0, stream,
                           emb, means, covs, n_ptr, out_means, out_covs);
    }
}